// Round 3
// baseline (404.029 us; speedup 1.0000x reference)
//
#include <hip/hip_runtime.h>
#include <stdint.h>

#define EPS 1e-8f

constexpr int C  = 256;     // channels (K dim)
constexpr int HW = 16384;   // pixels per image (M and N dims)
constexpr int BM = 128, BN = 128;

typedef __attribute__((ext_vector_type(8))) short short8;
typedef __attribute__((ext_vector_type(4))) float floatx4;
typedef unsigned short u16;
typedef unsigned int u32;
typedef unsigned long long u64;

__device__ inline u16 f2bf(float x) {   // RNE float -> bf16 bits (finite inputs)
    unsigned u = __float_as_uint(x);
    unsigned r = (u + 0x7FFFu + ((u >> 16) & 1u)) >> 16;
    return (u16)r;
}

__device__ inline unsigned mapf(float f) {  // monotone float -> uint (for max)
    unsigned u = __float_as_uint(f);
    return (u & 0x80000000u) ? ~u : (u | 0x80000000u);
}

#define GLD16(gp, lp) __builtin_amdgcn_global_load_lds( \
    (const __attribute__((address_space(1))) void*)(gp), \
    (__attribute__((address_space(3))) void*)(lp), 16, 0, 0)

// ---------------------------------------------------------------------------
// P1: per-pixel channel sum-of-squares for a and b, plus inverse norms.
__global__ void norms_kernel(const float* __restrict__ a, const float* __restrict__ b,
                             float* __restrict__ sumsq_a, float* __restrict__ sumsq_b,
                             float* __restrict__ inv_na, float* __restrict__ inv_nb) {
    __shared__ float pa[4][64], pb[4][64];
    int tid = threadIdx.x;
    int tc = tid >> 6, px = tid & 63;
    int p = blockIdx.x * 64 + px;
    float sa = 0.f, sb = 0.f;
    for (int c = tc * 64; c < tc * 64 + 64; ++c) {
        float va = a[(size_t)c * HW + p]; sa += va * va;
        float vb = b[(size_t)c * HW + p]; sb += vb * vb;
    }
    pa[tc][px] = sa; pb[tc][px] = sb;
    __syncthreads();
    if (tid < 64) {
        float A = pa[0][px] + pa[1][px] + pa[2][px] + pa[3][px];
        float B = pb[0][px] + pb[1][px] + pb[2][px] + pb[3][px];
        sumsq_a[p] = A; sumsq_b[p] = B;
        inv_na[p] = 1.0f / (sqrtf(A + EPS) + EPS);
        inv_nb[p] = 1.0f / (sqrtf(B + EPS) + EPS);
    }
}

// ---------------------------------------------------------------------------
// P2: transpose [c][p] -> [p][c], normalize, cast to bf16. z selects a vs b.
__global__ void transpose_norm2(const float* __restrict__ a, const float* __restrict__ b,
                                const float* __restrict__ inv_na, const float* __restrict__ inv_nb,
                                u16* __restrict__ aT, u16* __restrict__ bT) {
    const float* x     = blockIdx.z ? b : a;
    const float* inv_n = blockIdx.z ? inv_nb : inv_na;
    u16*         xT    = blockIdx.z ? bT : aT;
    __shared__ float tile[32][33];
    int tx = threadIdx.x, ty = threadIdx.y;
    int p0 = blockIdx.x * 32, c0 = blockIdx.y * 32;
    int p = p0 + tx;
    float inv = inv_n[p];
    #pragma unroll
    for (int i = 0; i < 4; ++i) {
        int c = c0 + ty + i * 8;
        tile[ty + i * 8][tx] = x[(size_t)c * HW + p] * inv;
    }
    __syncthreads();
    #pragma unroll
    for (int i = 0; i < 4; ++i) {
        int pr = p0 + ty + i * 8;
        int cc = c0 + tx;
        xT[(size_t)pr * C + cc] = f2bf(tile[tx][ty + i * 8]);
    }
}

// ---------------------------------------------------------------------------
// G: fused GEMM (S = aT . bT^T over K=256) + per-row argmax.
// 512 threads = 8 waves in 2(m) x 4(n); wave tile 64x32; K-loop = 2 x BK=128.
// LDS 64KB: A,B each 32 slabs of 1KB in MFMA fragment order: lane l's 16B of
// slab (rowgrp,ks) = X[row = rowgrp*16 + (l&15)][col = ks*32 + (l>>4)*8].
// Staging gathers on the GLOBAL side; LDS side is uniform_base + lane*16.
// Fragment ds_read_b128 is lane-consecutive => conflict-free (verified R2: 0).
// 64KB LDS => 2 blocks/CU co-resident => drains overlap the other block's MFMA.
__global__ __launch_bounds__(512) void gemm_argmax(const u16* __restrict__ aT,
                                                   const u16* __restrict__ bT,
                                                   u64* __restrict__ packed) {
    __shared__ union { u16 ab[32768]; u64 cand[BM][64]; } sm;   // 64 KB
    const int tid = threadIdx.x;
    const int w = tid >> 6, lane = tid & 63;
    const int q4 = lane >> 4, r15 = lane & 15;
    const int wm = w >> 2, wn = w & 3;           // 2 x 4 wave grid
    const int p0 = blockIdx.y * BM, q0 = blockIdx.x * BN;

    u16* ldsA = sm.ab;             // slabs (rowgrp 0..7, ks 0..3): rowgrp*4+ks
    u16* ldsB = sm.ab + 16384;

    // wave w stages rows [w*16, w*16+16) of both tiles, 4 k-chunks per iter
    const u16* gA = aT + (u32)(p0 + w * 16 + r15) * C + q4 * 8;
    const u16* gB = bT + (u32)(q0 + w * 16 + r15) * C + q4 * 8;
    u16* lA = ldsA + w * 4 * 512 + lane * 8;
    u16* lB = ldsB + w * 4 * 512 + lane * 8;

    floatx4 acc[4][2] = {};

    #pragma unroll
    for (int it = 0; it < 2; ++it) {
        const int k0 = it * 128;
        #pragma unroll
        for (int ks = 0; ks < 4; ++ks) {
            GLD16(gA + k0 + ks * 32, lA + ks * 512);
            GLD16(gB + k0 + ks * 32, lB + ks * 512);
        }
        __syncthreads();   // drains vmcnt; 2nd resident block computes meanwhile

        #pragma unroll
        for (int ks = 0; ks < 4; ++ks) {
            short8 af[4], bf[2];
            #pragma unroll
            for (int mi = 0; mi < 4; ++mi)
                af[mi] = *(const short8*)&ldsA[((wm * 4 + mi) * 4 + ks) * 512 + lane * 8];
            #pragma unroll
            for (int ni = 0; ni < 2; ++ni)
                bf[ni] = *(const short8*)&ldsB[((wn * 2 + ni) * 4 + ks) * 512 + lane * 8];
            #pragma unroll
            for (int mi = 0; mi < 4; ++mi)
                #pragma unroll
                for (int ni = 0; ni < 2; ++ni)
                    acc[mi][ni] = __builtin_amdgcn_mfma_f32_16x16x32_bf16(af[mi], bf[ni], acc[mi][ni], 0, 0, 0);
        }
        __syncthreads();
    }

    // epilogue phase 1: per-lane best over ni for each of its 16 rows -> LDS
    // D layout: col = lane&15 (n), row = q4*4+reg (m) within each 16x16 tile.
    #pragma unroll
    for (int mi = 0; mi < 4; ++mi) {
        #pragma unroll
        for (int reg = 0; reg < 4; ++reg) {
            int rowl = wm * 64 + mi * 16 + q4 * 4 + reg;
            u64 best = 0;
            #pragma unroll
            for (int ni = 0; ni < 2; ++ni) {
                float v = acc[mi][ni][reg];
                unsigned qc = (unsigned)(q0 + wn * 32 + ni * 16 + r15);
                u64 pk = ((u64)mapf(v) << 32) | (u64)(0xFFFFFFFFu - qc);  // ties -> smallest q
                best = best > pk ? best : pk;
            }
            sm.cand[rowl][wn * 16 + r15] = best;
        }
    }
    __syncthreads();
    // phase 2: 4 threads per row reduce 64 candidates (staggered), 1 atomic/row
    {
        int row = tid >> 2, qt = tid & 3;
        u64 best = 0;
        #pragma unroll
        for (int j = 0; j < 16; ++j) {
            int col = qt * 16 + ((j + row) & 15);
            u64 v = sm.cand[row][col];
            best = best > v ? best : v;
        }
        u64 o = __shfl_xor(best, 1); best = best > o ? best : o;
        o = __shfl_xor(best, 2);     best = best > o ? best : o;
        if (qt == 0) atomicMax(&packed[p0 + row], best);
    }
}

// ---------------------------------------------------------------------------
// L: exact fp32 loss. block = 4 c-chunks x 64 pixels, grid = HW/64.
__global__ void loss_kernel(const float* __restrict__ a, const float* __restrict__ b,
                            const u64* __restrict__ packed,
                            const float* __restrict__ sumsq_a, const float* __restrict__ sumsq_b,
                            float* __restrict__ out) {
    __shared__ float part[4][64];
    int tid = threadIdx.x;
    int tc = tid >> 6, px = tid & 63;
    int p = blockIdx.x * 64 + px;
    unsigned q = 0xFFFFFFFFu - (unsigned)(packed[p] & 0xFFFFFFFFull);
    float dot = 0.f;
    for (int c = tc * 64; c < tc * 64 + 64; ++c)
        dot += a[(size_t)c * HW + p] * b[(size_t)c * HW + q];
    part[tc][px] = dot;
    __syncthreads();
    if (tid < 64) {
        float d = part[0][px] + part[1][px] + part[2][px] + part[3][px];
        float an = sqrtf(sumsq_a[p]);
        float tn = sqrtf(sumsq_b[q]);
        float cossim = d / ((an + EPS) * (tn + EPS));
        float v = (1.0f - cossim) * (1.0f / (float)HW);
        #pragma unroll
        for (int m = 1; m < 64; m <<= 1) v += __shfl_xor(v, m);
        if (tid == 0) atomicAdd(out, v);
    }
}

// ---------------------------------------------------------------------------
extern "C" void kernel_launch(void* const* d_in, const int* in_sizes, int n_in,
                              void* d_out, int out_size, void* d_ws, size_t ws_size,
                              hipStream_t stream) {
    const float* a = (const float*)d_in[0];
    const float* b = (const float*)d_in[1];
    float* out = (float*)d_out;
    char* ws = (char*)d_ws;

    u16*   aT      = (u16*)ws;                                   // 8 MB
    u16*   bT      = (u16*)(ws + (size_t)8 * 1024 * 1024);       // 8 MB
    float* sumsq_a = (float*)(ws + (size_t)16 * 1024 * 1024);    // 64 KB
    float* sumsq_b = sumsq_a + HW;
    float* inv_na  = sumsq_b + HW;
    float* inv_nb  = inv_na + HW;
    u64*   packed  = (u64*)(inv_nb + HW);                        // 128 KB

    hipMemsetAsync(out, 0, sizeof(float), stream);
    hipMemsetAsync(packed, 0, (size_t)HW * sizeof(u64), stream);

    norms_kernel<<<dim3(HW / 64), 256, 0, stream>>>(a, b, sumsq_a, sumsq_b, inv_na, inv_nb);
    transpose_norm2<<<dim3(HW / 32, C / 32, 2), dim3(32, 8), 0, stream>>>(a, b, inv_na, inv_nb, aT, bT);
    gemm_argmax<<<dim3(HW / BN, HW / BM), 512, 0, stream>>>(aT, bT, packed);
    loss_kernel<<<dim3(HW / 64), 256, 0, stream>>>(a, b, packed, sumsq_a, sumsq_b, out);
}

// Round 4
// 361.758 us; speedup vs baseline: 1.1169x; 1.1169x over previous
//
#include <hip/hip_runtime.h>
#include <stdint.h>

#define EPS 1e-8f

constexpr int C  = 256;     // channels (K dim)
constexpr int HW = 16384;   // pixels per image (M and N dims)
constexpr int BM = 128, BN = 128, BK = 64;

typedef __attribute__((ext_vector_type(8))) short short8;
typedef __attribute__((ext_vector_type(4))) float floatx4;
typedef unsigned short u16;
typedef unsigned int u32;
typedef unsigned long long u64;

__device__ inline u16 f2bf(float x) {   // RNE float -> bf16 bits (finite inputs)
    unsigned u = __float_as_uint(x);
    unsigned r = (u + 0x7FFFu + ((u >> 16) & 1u)) >> 16;
    return (u16)r;
}

__device__ inline unsigned mapf(float f) {  // monotone float -> uint (for max)
    unsigned u = __float_as_uint(f);
    return (u & 0x80000000u) ? ~u : (u | 0x80000000u);
}

#define GLD16(gp, lp) __builtin_amdgcn_global_load_lds( \
    (const __attribute__((address_space(1))) void*)(gp), \
    (__attribute__((address_space(3))) void*)(lp), 16, 0, 0)

// ---------------------------------------------------------------------------
// P1: per-pixel channel sum-of-squares for a and b, plus inverse norms.
__global__ void norms_kernel(const float* __restrict__ a, const float* __restrict__ b,
                             float* __restrict__ sumsq_a, float* __restrict__ sumsq_b,
                             float* __restrict__ inv_na, float* __restrict__ inv_nb) {
    __shared__ float pa[4][64], pb[4][64];
    int tid = threadIdx.x;
    int tc = tid >> 6, px = tid & 63;
    int p = blockIdx.x * 64 + px;
    float sa = 0.f, sb = 0.f;
    for (int c = tc * 64; c < tc * 64 + 64; ++c) {
        float va = a[(size_t)c * HW + p]; sa += va * va;
        float vb = b[(size_t)c * HW + p]; sb += vb * vb;
    }
    pa[tc][px] = sa; pb[tc][px] = sb;
    __syncthreads();
    if (tid < 64) {
        float A = pa[0][px] + pa[1][px] + pa[2][px] + pa[3][px];
        float B = pb[0][px] + pb[1][px] + pb[2][px] + pb[3][px];
        sumsq_a[p] = A; sumsq_b[p] = B;
        inv_na[p] = 1.0f / (sqrtf(A + EPS) + EPS);
        inv_nb[p] = 1.0f / (sqrtf(B + EPS) + EPS);
    }
}

// ---------------------------------------------------------------------------
// P2: transpose [c][p] -> [p][c], normalize, cast to bf16. z selects a vs b.
__global__ void transpose_norm2(const float* __restrict__ a, const float* __restrict__ b,
                                const float* __restrict__ inv_na, const float* __restrict__ inv_nb,
                                u16* __restrict__ aT, u16* __restrict__ bT) {
    const float* x     = blockIdx.z ? b : a;
    const float* inv_n = blockIdx.z ? inv_nb : inv_na;
    u16*         xT    = blockIdx.z ? bT : aT;
    __shared__ float tile[32][33];
    int tx = threadIdx.x, ty = threadIdx.y;
    int p0 = blockIdx.x * 32, c0 = blockIdx.y * 32;
    int p = p0 + tx;
    float inv = inv_n[p];
    #pragma unroll
    for (int i = 0; i < 4; ++i) {
        int c = c0 + ty + i * 8;
        tile[ty + i * 8][tx] = x[(size_t)c * HW + p] * inv;
    }
    __syncthreads();
    #pragma unroll
    for (int i = 0; i < 4; ++i) {
        int pr = p0 + ty + i * 8;
        int cc = c0 + tx;
        xT[(size_t)pr * C + cc] = f2bf(tile[tx][ty + i * 8]);
    }
}

// ---------------------------------------------------------------------------
// G: fused GEMM (S = aT . bT^T over K=256) + per-row argmax (R2 structure:
// 256 thr = 2x2 waves of 64x64, BK=64, fragment-order 1KB LDS slabs,
// conflict-free ds_read_b128 — verified 0 conflicts in R2).
// NEW: XCD-aware swizzle. bid%8 = XCD; each XCD owns an M-stripe of 16
// m-tiles (2048 rows = 1MB of aT, resident in its 4MB L2) and sweeps N
// slowly, so staging is L2-served instead of Infinity-Cache-served.
__global__ __launch_bounds__(256) void gemm_argmax(const u16* __restrict__ aT,
                                                   const u16* __restrict__ bT,
                                                   u64* __restrict__ packed) {
    __shared__ union { u16 ab[32 * 512]; u64 cand[BM][32]; } sm;   // 32 KB
    const int tid = threadIdx.x;
    const int w = tid >> 6, lane = tid & 63;
    const int q4 = lane >> 4, r15 = lane & 15;
    const int wm = w >> 1, wn = w & 1;

    const u32 bid = blockIdx.x;
    const u32 xcd = bid & 7, local = bid >> 3;
    const int mt = (int)(xcd * 16 + (local & 15));   // M-stripe per XCD
    const int nt = (int)(local >> 4);                // slow N sweep
    const int p0 = mt * BM, q0 = nt * BN;

    u16* ldsA = sm.ab;              // slabs 0..15  : A (wm*8 + mi*2 + ks)
    u16* ldsB = sm.ab + 16 * 512;   // slabs 0..15  : B (wn*8 + ni*2 + ks)

    // wave w stages A slabs w*4+i and B slabs w*4+i (i=0..3), 8 instrs/iter.
    // slab s: tile-row = (s>>3)*64 + ((s>>1)&3)*16 + (l&15);
    //         tile-col(u16) = (s&1)*32 + (l>>4)*8
    u32 offA[4], offB[4];
    #pragma unroll
    for (int i = 0; i < 4; ++i) {
        int s = w * 4 + i;
        int rowt = (s >> 3) * 64 + ((s >> 1) & 3) * 16 + r15;
        int colt = (s & 1) * 32 + q4 * 8;
        offA[i] = (u32)(p0 + rowt) * C + colt;
        offB[i] = (u32)(q0 + rowt) * C + colt;
    }

    floatx4 acc[4][4] = {};

    for (int it = 0; it < 4; ++it) {
        const int k0 = it * BK;
        #pragma unroll
        for (int i = 0; i < 4; ++i) {
            int s = w * 4 + i;
            GLD16(aT + offA[i] + k0, ldsA + s * 512 + lane * 8);
            GLD16(bT + offB[i] + k0, ldsB + s * 512 + lane * 8);
        }
        __syncthreads();   // compiler drains vmcnt before barrier

        #pragma unroll
        for (int ks = 0; ks < 2; ++ks) {
            short8 af[4], bf[4];
            #pragma unroll
            for (int mi = 0; mi < 4; ++mi)
                af[mi] = *(const short8*)&ldsA[(wm * 8 + mi * 2 + ks) * 512 + lane * 8];
            #pragma unroll
            for (int ni = 0; ni < 4; ++ni)
                bf[ni] = *(const short8*)&ldsB[(wn * 8 + ni * 2 + ks) * 512 + lane * 8];
            #pragma unroll
            for (int mi = 0; mi < 4; ++mi)
                #pragma unroll
                for (int ni = 0; ni < 4; ++ni)
                    acc[mi][ni] = __builtin_amdgcn_mfma_f32_16x16x32_bf16(af[mi], bf[ni], acc[mi][ni], 0, 0, 0);
        }
        __syncthreads();
    }

    // epilogue phase 1: per-lane best over ni for each of its 16 rows -> LDS
    // D layout: col = lane&15 (n), row = q4*4+reg (m) within each 16x16 tile.
    #pragma unroll
    for (int mi = 0; mi < 4; ++mi) {
        #pragma unroll
        for (int reg = 0; reg < 4; ++reg) {
            int rowl = wm * 64 + mi * 16 + q4 * 4 + reg;
            u64 best = 0;
            #pragma unroll
            for (int ni = 0; ni < 4; ++ni) {
                float v = acc[mi][ni][reg];
                unsigned qc = (unsigned)(q0 + wn * 64 + ni * 16 + r15);
                u64 pk = ((u64)mapf(v) << 32) | (u64)(0xFFFFFFFFu - qc);  // ties -> smallest q
                best = best > pk ? best : pk;
            }
            sm.cand[rowl][wn * 16 + r15] = best;
        }
    }
    __syncthreads();
    // phase 2: 2 threads per row reduce the 32 candidates (diagonal-staggered
    // columns to spread banks), one atomic per row.
    {
        int row = tid >> 1, half = tid & 1;
        u64 best = 0;
        #pragma unroll
        for (int j = 0; j < 16; ++j) {
            int col = half * 16 + ((j + row) & 15);
            u64 v = sm.cand[row][col];
            best = best > v ? best : v;
        }
        u64 o = __shfl_xor(best, 1);
        best = best > o ? best : o;
        if (half == 0) atomicMax(&packed[p0 + row], best);
    }
}

// ---------------------------------------------------------------------------
// L: exact fp32 loss. block = 4 c-chunks x 64 pixels, grid = HW/64.
__global__ void loss_kernel(const float* __restrict__ a, const float* __restrict__ b,
                            const u64* __restrict__ packed,
                            const float* __restrict__ sumsq_a, const float* __restrict__ sumsq_b,
                            float* __restrict__ out) {
    __shared__ float part[4][64];
    int tid = threadIdx.x;
    int tc = tid >> 6, px = tid & 63;
    int p = blockIdx.x * 64 + px;
    unsigned q = 0xFFFFFFFFu - (unsigned)(packed[p] & 0xFFFFFFFFull);
    float dot = 0.f;
    for (int c = tc * 64; c < tc * 64 + 64; ++c)
        dot += a[(size_t)c * HW + p] * b[(size_t)c * HW + q];
    part[tc][px] = dot;
    __syncthreads();
    if (tid < 64) {
        float d = part[0][px] + part[1][px] + part[2][px] + part[3][px];
        float an = sqrtf(sumsq_a[p]);
        float tn = sqrtf(sumsq_b[q]);
        float cossim = d / ((an + EPS) * (tn + EPS));
        float v = (1.0f - cossim) * (1.0f / (float)HW);
        #pragma unroll
        for (int m = 1; m < 64; m <<= 1) v += __shfl_xor(v, m);
        if (tid == 0) atomicAdd(out, v);
    }
}

// ---------------------------------------------------------------------------
extern "C" void kernel_launch(void* const* d_in, const int* in_sizes, int n_in,
                              void* d_out, int out_size, void* d_ws, size_t ws_size,
                              hipStream_t stream) {
    const float* a = (const float*)d_in[0];
    const float* b = (const float*)d_in[1];
    float* out = (float*)d_out;
    char* ws = (char*)d_ws;

    u16*   aT      = (u16*)ws;                                   // 8 MB
    u16*   bT      = (u16*)(ws + (size_t)8 * 1024 * 1024);       // 8 MB
    float* sumsq_a = (float*)(ws + (size_t)16 * 1024 * 1024);    // 64 KB
    float* sumsq_b = sumsq_a + HW;
    float* inv_na  = sumsq_b + HW;
    float* inv_nb  = inv_na + HW;
    u64*   packed  = (u64*)(inv_nb + HW);                        // 128 KB

    hipMemsetAsync(out, 0, sizeof(float), stream);
    hipMemsetAsync(packed, 0, (size_t)HW * sizeof(u64), stream);

    norms_kernel<<<dim3(HW / 64), 256, 0, stream>>>(a, b, sumsq_a, sumsq_b, inv_na, inv_nb);
    transpose_norm2<<<dim3(HW / 32, C / 32, 2), dim3(32, 8), 0, stream>>>(a, b, inv_na, inv_nb, aT, bT);
    gemm_argmax<<<dim3((HW / BM) * (HW / BN)), 256, 0, stream>>>(aT, bT, packed);
    loss_kernel<<<dim3(HW / 64), 256, 0, stream>>>(a, b, packed, sumsq_a, sumsq_b, out);
}

// Round 5
// 310.337 us; speedup vs baseline: 1.3019x; 1.1657x over previous
//
#include <hip/hip_runtime.h>
#include <stdint.h>

#define EPS 1e-8f

constexpr int C  = 256;     // channels (K dim)
constexpr int HW = 16384;   // pixels per image (M and N dims)
constexpr int BM = 128, BN = 128;

typedef __attribute__((ext_vector_type(8))) short short8;
typedef __attribute__((ext_vector_type(4))) float floatx4;
typedef unsigned short u16;
typedef unsigned int u32;
typedef unsigned long long u64;

__device__ inline u16 f2bf(float x) {   // RNE float -> bf16 bits (finite inputs)
    unsigned u = __float_as_uint(x);
    unsigned r = (u + 0x7FFFu + ((u >> 16) & 1u)) >> 16;
    return (u16)r;
}

// ---------------------------------------------------------------------------
// P1: per-pixel channel sum-of-squares for a and b; inverse norm for b only
// (argmax over q is invariant to per-p scaling of a, so a stays raw).
__global__ void norms_kernel(const float* __restrict__ a, const float* __restrict__ b,
                             float* __restrict__ sumsq_a, float* __restrict__ sumsq_b,
                             float* __restrict__ inv_nb) {
    __shared__ float pa[4][64], pb[4][64];
    int tid = threadIdx.x;
    int tc = tid >> 6, px = tid & 63;
    int p = blockIdx.x * 64 + px;
    float sa = 0.f, sb = 0.f;
    for (int c = tc * 64; c < tc * 64 + 64; ++c) {
        float va = a[(size_t)c * HW + p]; sa += va * va;
        float vb = b[(size_t)c * HW + p]; sb += vb * vb;
    }
    pa[tc][px] = sa; pb[tc][px] = sb;
    __syncthreads();
    if (tid < 64) {
        float A = pa[0][px] + pa[1][px] + pa[2][px] + pa[3][px];
        float B = pb[0][px] + pb[1][px] + pb[2][px] + pb[3][px];
        sumsq_a[p] = A; sumsq_b[p] = B;
        inv_nb[p] = 1.0f / (sqrtf(B + EPS) + EPS);
    }
}

// ---------------------------------------------------------------------------
// P2: transpose [c][p] -> MFMA-fragment-order [slab][lane][j] bf16.
// Fragment (g, ch): g = pixel-group of 16, ch = 32-channel chunk. Element
// (pixel pr, channel cc) lives at ((g*8+ch)*512) + lane*8 + j with
// lane = (pr&15) + ((cc>>3)&3)*16, j = cc&7  — exactly the 16x16x32 A/B
// fragment layout, so the GEMM can load fragments straight from global.
__global__ void transpose_frag(const float* __restrict__ a, const float* __restrict__ b,
                               const float* __restrict__ inv_nb,
                               u16* __restrict__ aF, u16* __restrict__ bF) {
    const float* x  = blockIdx.z ? b : a;
    u16*         xF = blockIdx.z ? bF : aF;
    __shared__ float tile[32][33];
    int tx = threadIdx.x, ty = threadIdx.y;
    int p0 = blockIdx.x * 32, c0 = blockIdx.y * 32;
    int p = p0 + tx;
    float inv = blockIdx.z ? inv_nb[p] : 1.0f;   // a: raw (scale-invariant argmax)
    #pragma unroll
    for (int i = 0; i < 4; ++i) {
        int c = c0 + ty + i * 8;
        tile[ty + i * 8][tx] = x[(size_t)c * HW + p] * inv;
    }
    __syncthreads();
    #pragma unroll
    for (int i = 0; i < 4; ++i) {
        int pr = p0 + ty + i * 8;
        int cc = c0 + tx;
        int g = pr >> 4, ch = cc >> 5;
        int lane2 = (pr & 15) + (((cc >> 3) & 3) << 4);
        int j = cc & 7;
        xF[((size_t)(g * 8 + ch) << 9) + lane2 * 8 + j] = f2bf(tile[tx][ty + i * 8]);
    }
}

// ---------------------------------------------------------------------------
// G: fused GEMM (S = A . B^T over K=256) + per-row argmax.
// NO LDS staging, NO K-loop barriers: operands are pre-swizzled to fragment
// order in global memory, so each wave loads its fragments directly to VGPRs
// (global_load_dwordx4, coalesced 1KB/instr) and free-runs. The compiler
// pipelines loads with fine-grained vmcnt. LDS only holds the 32KB argmax
// candidate array. 2-stage ping-pong keeps VGPRs bounded.
__global__ __launch_bounds__(256, 3) void gemm_argmax(const u16* __restrict__ aF,
                                                      const u16* __restrict__ bF,
                                                      u64* __restrict__ packed) {
    __shared__ u64 cand[BM][32];   // 32 KB
    const int tid = threadIdx.x;
    const int w = tid >> 6, lane = tid & 63;
    const int q4 = lane >> 4, r15 = lane & 15;
    const int wm = w >> 1, wn = w & 1;

    const u32 bid = blockIdx.x;
    const u32 xcd = bid & 7, local = bid >> 3;
    const int mt = (int)(xcd * 16 + (local & 15));   // M-stripe per XCD (L2 locality)
    const int nt = (int)(local >> 4);                // slow N sweep
    const int p0 = mt * BM, q0 = nt * BN;

    // wave (wm,wn): A rows wm*64..+64 -> groups (mt*8 + wm*4 + mi), mi 0..3
    const u16* gA = aF + ((size_t)(mt * 8 + wm * 4) * 8) * 512 + (u32)lane * 8;
    const u16* gB = bF + ((size_t)(nt * 8 + wn * 4) * 8) * 512 + (u32)lane * 8;
    // fragment (x, c) at  g? + (x*8 + c)*512,  c = 0..7 (K chunks of 32)

    floatx4 acc[4][4] = {};
    short8 afr[2][4], bfr[2][4];
    #pragma unroll
    for (int x = 0; x < 4; ++x) {
        afr[0][x] = *(const short8*)(gA + (u32)(x * 8) * 512);
        bfr[0][x] = *(const short8*)(gB + (u32)(x * 8) * 512);
    }
    #pragma unroll
    for (int c = 0; c < 8; ++c) {
        const int cur = c & 1, nxt = cur ^ 1;
        if (c < 7) {
            #pragma unroll
            for (int x = 0; x < 4; ++x) {
                afr[nxt][x] = *(const short8*)(gA + (u32)(x * 8 + c + 1) * 512);
                bfr[nxt][x] = *(const short8*)(gB + (u32)(x * 8 + c + 1) * 512);
            }
        }
        #pragma unroll
        for (int mi = 0; mi < 4; ++mi)
            #pragma unroll
            for (int ni = 0; ni < 4; ++ni)
                acc[mi][ni] = __builtin_amdgcn_mfma_f32_16x16x32_bf16(afr[cur][mi], bfr[cur][ni], acc[mi][ni], 0, 0, 0);
    }

    // epilogue phase 1: cheap per-lane argmax (float cmp + index select),
    // pack u64 once per row.  D layout: col = lane&15, row = q4*4+reg.
    #pragma unroll
    for (int mi = 0; mi < 4; ++mi) {
        #pragma unroll
        for (int reg = 0; reg < 4; ++reg) {
            float bv = acc[mi][0][reg];
            u32 bq = (u32)(q0 + wn * 64 + r15);
            #pragma unroll
            for (int ni = 1; ni < 4; ++ni) {
                float v = acc[mi][ni][reg];
                u32 qc = (u32)(q0 + wn * 64 + ni * 16 + r15);
                bool gt = v > bv;              // strict: ties keep smaller q
                bv = gt ? v : bv;
                bq = gt ? qc : bq;
            }
            int rowl = wm * 64 + mi * 16 + q4 * 4 + reg;
            u32 m = __float_as_uint(bv);
            m = m ^ (u32)(((int)m >> 31) | 0x80000000u);   // monotone map
            cand[rowl][wn * 16 + r15] = ((u64)m << 32) | (u64)(0xFFFFFFFFu - bq);
        }
    }
    __syncthreads();
    // phase 2: 2 threads per row reduce the 32 candidates (staggered), 1 atomic/row
    {
        int row = tid >> 1, half = tid & 1;
        u64 best = 0;
        #pragma unroll
        for (int j = 0; j < 16; ++j) {
            int col = half * 16 + ((j + row) & 15);
            u64 v = cand[row][col];
            best = best > v ? best : v;
        }
        u64 o = __shfl_xor(best, 1);
        best = best > o ? best : o;
        if (half == 0) atomicMax(&packed[p0 + row], best);
    }
}

// ---------------------------------------------------------------------------
// L: exact fp32 loss. block = 4 c-chunks x 64 pixels, grid = HW/64.
__global__ void loss_kernel(const float* __restrict__ a, const float* __restrict__ b,
                            const u64* __restrict__ packed,
                            const float* __restrict__ sumsq_a, const float* __restrict__ sumsq_b,
                            float* __restrict__ out) {
    __shared__ float part[4][64];
    int tid = threadIdx.x;
    int tc = tid >> 6, px = tid & 63;
    int p = blockIdx.x * 64 + px;
    unsigned q = 0xFFFFFFFFu - (unsigned)(packed[p] & 0xFFFFFFFFull);
    float dot = 0.f;
    for (int c = tc * 64; c < tc * 64 + 64; ++c)
        dot += a[(size_t)c * HW + p] * b[(size_t)c * HW + q];
    part[tc][px] = dot;
    __syncthreads();
    if (tid < 64) {
        float d = part[0][px] + part[1][px] + part[2][px] + part[3][px];
        float an = sqrtf(sumsq_a[p]);
        float tn = sqrtf(sumsq_b[q]);
        float cossim = d / ((an + EPS) * (tn + EPS));
        float v = (1.0f - cossim) * (1.0f / (float)HW);
        #pragma unroll
        for (int m = 1; m < 64; m <<= 1) v += __shfl_xor(v, m);
        if (tid == 0) atomicAdd(out, v);
    }
}

// ---------------------------------------------------------------------------
extern "C" void kernel_launch(void* const* d_in, const int* in_sizes, int n_in,
                              void* d_out, int out_size, void* d_ws, size_t ws_size,
                              hipStream_t stream) {
    const float* a = (const float*)d_in[0];
    const float* b = (const float*)d_in[1];
    float* out = (float*)d_out;
    char* ws = (char*)d_ws;

    u16*   aF      = (u16*)ws;                                   // 8 MB
    u16*   bF      = (u16*)(ws + (size_t)8 * 1024 * 1024);       // 8 MB
    float* sumsq_a = (float*)(ws + (size_t)16 * 1024 * 1024);    // 64 KB
    float* sumsq_b = sumsq_a + HW;
    float* inv_nb  = sumsq_b + HW;
    u64*   packed  = (u64*)(inv_nb + HW);                        // 128 KB

    hipMemsetAsync(out, 0, sizeof(float), stream);
    hipMemsetAsync(packed, 0, (size_t)HW * sizeof(u64), stream);

    norms_kernel<<<dim3(HW / 64), 256, 0, stream>>>(a, b, sumsq_a, sumsq_b, inv_nb);
    transpose_frag<<<dim3(HW / 32, C / 32, 2), dim3(32, 8), 0, stream>>>(a, b, inv_nb, aF, bF);
    gemm_argmax<<<dim3((HW / BM) * (HW / BN)), 256, 0, stream>>>(aF, bF, packed);
    loss_kernel<<<dim3(HW / 64), 256, 0, stream>>>(a, b, packed, sumsq_a, sumsq_b, out);
}

// Round 6
// 226.171 us; speedup vs baseline: 1.7864x; 1.3721x over previous
//
#include <hip/hip_runtime.h>
#include <hip/hip_fp8.h>
#include <stdint.h>

#define EPS 1e-8f

constexpr int C  = 256;     // channels (K dim)
constexpr int HW = 16384;   // pixels per image (M and N dims)
constexpr int BM = 128, BN = 128;

typedef __attribute__((ext_vector_type(4))) float floatx4;
typedef long long llong2 __attribute__((ext_vector_type(2)));   // 16B = 2 fp8 k-chunks
typedef unsigned char u8;
typedef unsigned int u32;
typedef unsigned long long u64;

__device__ inline u8 f2fp8(float x) {   // OCP e4m3 (gfx950 HW cvt)
    __hip_fp8_e4m3 h(x);
    return h.__x;
}

// ---------------------------------------------------------------------------
// P1: per-pixel channel sum-of-squares for a and b; inverse norm for b only
// (argmax over q is invariant to per-p scaling of a, so a stays raw).
__global__ void norms_kernel(const float* __restrict__ a, const float* __restrict__ b,
                             float* __restrict__ sumsq_a, float* __restrict__ sumsq_b,
                             float* __restrict__ inv_nb) {
    __shared__ float pa[4][64], pb[4][64];
    int tid = threadIdx.x;
    int tc = tid >> 6, px = tid & 63;
    int p = blockIdx.x * 64 + px;
    float sa = 0.f, sb = 0.f;
    for (int c = tc * 64; c < tc * 64 + 64; ++c) {
        float va = a[(size_t)c * HW + p]; sa += va * va;
        float vb = b[(size_t)c * HW + p]; sb += vb * vb;
    }
    pa[tc][px] = sa; pb[tc][px] = sb;
    __syncthreads();
    if (tid < 64) {
        float A = pa[0][px] + pa[1][px] + pa[2][px] + pa[3][px];
        float B = pb[0][px] + pb[1][px] + pb[2][px] + pb[3][px];
        sumsq_a[p] = A; sumsq_b[p] = B;
        inv_nb[p] = 1.0f / (sqrtf(B + EPS) + EPS);
    }
}

// ---------------------------------------------------------------------------
// P2: transpose [c][p] -> fp8 MFMA-fragment order, two k-chunks packed per
// 16B lane slot. Slab (g, cp) is 1KB: lane l's 16B = [chunk 2cp: 8B][chunk
// 2cp+1: 8B], with lane = (pr&15) + ((cc>>3)&3)*16, byte j = cc&7 — exactly
// the 16x16x32_fp8 A/B fragment layout, loadable straight to VGPRs.
__global__ void transpose_frag(const float* __restrict__ a, const float* __restrict__ b,
                               const float* __restrict__ inv_nb,
                               u8* __restrict__ aF, u8* __restrict__ bF) {
    const float* x  = blockIdx.z ? b : a;
    u8*          xF = blockIdx.z ? bF : aF;
    __shared__ float tile[32][33];
    int tx = threadIdx.x, ty = threadIdx.y;
    int p0 = blockIdx.x * 32, c0 = blockIdx.y * 32;
    int p = p0 + tx;
    float inv = blockIdx.z ? inv_nb[p] : 1.0f;   // a: raw (scale-invariant argmax)
    #pragma unroll
    for (int i = 0; i < 4; ++i) {
        int c = c0 + ty + i * 8;
        tile[ty + i * 8][tx] = x[(size_t)c * HW + p] * inv;
    }
    __syncthreads();
    #pragma unroll
    for (int i = 0; i < 4; ++i) {
        int pr = p0 + ty + i * 8;
        int cc = c0 + tx;
        int g = pr >> 4;
        int ch = cc >> 5;                 // 32-channel chunk
        int cp = ch >> 1, half = ch & 1;  // chunk pair, half within pair
        int lane2 = (pr & 15) + (((cc >> 3) & 3) << 4);
        int j = cc & 7;
        xF[((size_t)(g * 4 + cp) << 10) + lane2 * 16 + half * 8 + j] =
            f2fp8(tile[tx][ty + i * 8]);
    }
}

// ---------------------------------------------------------------------------
// G: fused GEMM (S = A . B^T over K=256, fp8 e4m3) + per-row argmax.
// Barrier-free K-loop (verified R5): fragments load directly global->VGPR
// (global_load_dwordx4, 1KB/instr, each covering TWO k-chunks), waves
// free-run, compiler pipelines with fine-grained vmcnt. fp8 halves VMEM
// bytes vs bf16 at the same MFMA rate. LDS only holds the argmax array.
__global__ __launch_bounds__(256, 3) void gemm_argmax(const u8* __restrict__ aF,
                                                      const u8* __restrict__ bF,
                                                      u64* __restrict__ packed) {
    __shared__ u64 cand[BM][32];   // 32 KB
    const int tid = threadIdx.x;
    const int w = tid >> 6, lane = tid & 63;
    const int q4 = lane >> 4, r15 = lane & 15;
    const int wm = w >> 1, wn = w & 1;

    const u32 bid = blockIdx.x;
    const u32 xcd = bid & 7, local = bid >> 3;
    const int mt = (int)(xcd * 16 + (local & 15));   // M-stripe per XCD (L2 locality)
    const int nt = (int)(local >> 4);                // slow N sweep
    const int p0 = mt * BM, q0 = nt * BN;

    // wave (wm,wn): A groups mt*8 + wm*4 + mi; fragment (x, cp) at +(x*4+cp)*1KB
    const u8* gA = aF + ((size_t)(mt * 8 + wm * 4) * 4) * 1024 + (u32)lane * 16;
    const u8* gB = bF + ((size_t)(nt * 8 + wn * 4) * 4) * 1024 + (u32)lane * 16;

    floatx4 acc[4][4] = {};
    llong2 afr[2][4], bfr[2][4];
    #pragma unroll
    for (int x = 0; x < 4; ++x) {
        afr[0][x] = *(const llong2*)(gA + (u32)(x * 4) * 1024);
        bfr[0][x] = *(const llong2*)(gB + (u32)(x * 4) * 1024);
    }
    #pragma unroll
    for (int cp = 0; cp < 4; ++cp) {
        const int cur = cp & 1, nxt = cur ^ 1;
        if (cp < 3) {
            #pragma unroll
            for (int x = 0; x < 4; ++x) {
                afr[nxt][x] = *(const llong2*)(gA + (u32)(x * 4 + cp + 1) * 1024);
                bfr[nxt][x] = *(const llong2*)(gB + (u32)(x * 4 + cp + 1) * 1024);
            }
        }
        #pragma unroll
        for (int mi = 0; mi < 4; ++mi)
            #pragma unroll
            for (int ni = 0; ni < 4; ++ni)
                acc[mi][ni] = __builtin_amdgcn_mfma_f32_16x16x32_fp8_fp8(
                    afr[cur][mi].x, bfr[cur][ni].x, acc[mi][ni], 0, 0, 0);
        #pragma unroll
        for (int mi = 0; mi < 4; ++mi)
            #pragma unroll
            for (int ni = 0; ni < 4; ++ni)
                acc[mi][ni] = __builtin_amdgcn_mfma_f32_16x16x32_fp8_fp8(
                    afr[cur][mi].y, bfr[cur][ni].y, acc[mi][ni], 0, 0, 0);
    }

    // epilogue phase 1: per-lane argmax (float cmp + index select), pack u64
    // once per row. D layout: col = lane&15, row = q4*4+reg (dtype-independent).
    #pragma unroll
    for (int mi = 0; mi < 4; ++mi) {
        #pragma unroll
        for (int reg = 0; reg < 4; ++reg) {
            float bv = acc[mi][0][reg];
            u32 bq = (u32)(q0 + wn * 64 + r15);
            #pragma unroll
            for (int ni = 1; ni < 4; ++ni) {
                float v = acc[mi][ni][reg];
                u32 qc = (u32)(q0 + wn * 64 + ni * 16 + r15);
                bool gt = v > bv;              // strict: ties keep smaller q
                bv = gt ? v : bv;
                bq = gt ? qc : bq;
            }
            int rowl = wm * 64 + mi * 16 + q4 * 4 + reg;
            u32 m = __float_as_uint(bv);
            m = m ^ (u32)(((int)m >> 31) | 0x80000000u);   // monotone map
            cand[rowl][wn * 16 + r15] = ((u64)m << 32) | (u64)(0xFFFFFFFFu - bq);
        }
    }
    __syncthreads();
    // phase 2: 2 threads per row reduce the 32 candidates (staggered), 1 atomic/row
    {
        int row = tid >> 1, half = tid & 1;
        u64 best = 0;
        #pragma unroll
        for (int j = 0; j < 16; ++j) {
            int col = half * 16 + ((j + row) & 15);
            u64 v = cand[row][col];
            best = best > v ? best : v;
        }
        u64 o = __shfl_xor(best, 1);
        best = best > o ? best : o;
        if (half == 0) atomicMax(&packed[p0 + row], best);
    }
}

// ---------------------------------------------------------------------------
// L: exact fp32 loss. block = 4 c-chunks x 64 pixels, grid = HW/64.
__global__ void loss_kernel(const float* __restrict__ a, const float* __restrict__ b,
                            const u64* __restrict__ packed,
                            const float* __restrict__ sumsq_a, const float* __restrict__ sumsq_b,
                            float* __restrict__ out) {
    __shared__ float part[4][64];
    int tid = threadIdx.x;
    int tc = tid >> 6, px = tid & 63;
    int p = blockIdx.x * 64 + px;
    unsigned q = 0xFFFFFFFFu - (unsigned)(packed[p] & 0xFFFFFFFFull);
    float dot = 0.f;
    for (int c = tc * 64; c < tc * 64 + 64; ++c)
        dot += a[(size_t)c * HW + p] * b[(size_t)c * HW + q];
    part[tc][px] = dot;
    __syncthreads();
    if (tid < 64) {
        float d = part[0][px] + part[1][px] + part[2][px] + part[3][px];
        float an = sqrtf(sumsq_a[p]);
        float tn = sqrtf(sumsq_b[q]);
        float cossim = d / ((an + EPS) * (tn + EPS));
        float v = (1.0f - cossim) * (1.0f / (float)HW);
        #pragma unroll
        for (int m = 1; m < 64; m <<= 1) v += __shfl_xor(v, m);
        if (tid == 0) atomicAdd(out, v);
    }
}

// ---------------------------------------------------------------------------
extern "C" void kernel_launch(void* const* d_in, const int* in_sizes, int n_in,
                              void* d_out, int out_size, void* d_ws, size_t ws_size,
                              hipStream_t stream) {
    const float* a = (const float*)d_in[0];
    const float* b = (const float*)d_in[1];
    float* out = (float*)d_out;
    char* ws = (char*)d_ws;

    u8*    aF      = (u8*)ws;                                    // 4 MB
    u8*    bF      = (u8*)(ws + (size_t)4 * 1024 * 1024);        // 4 MB
    float* sumsq_a = (float*)(ws + (size_t)8 * 1024 * 1024);     // 64 KB
    float* sumsq_b = sumsq_a + HW;
    float* inv_nb  = sumsq_b + HW;
    u64*   packed  = (u64*)(inv_nb + HW);                        // 128 KB

    hipMemsetAsync(out, 0, sizeof(float), stream);
    hipMemsetAsync(packed, 0, (size_t)HW * sizeof(u64), stream);

    norms_kernel<<<dim3(HW / 64), 256, 0, stream>>>(a, b, sumsq_a, sumsq_b, inv_nb);
    transpose_frag<<<dim3(HW / 32, C / 32, 2), dim3(32, 8), 0, stream>>>(a, b, inv_nb, aF, bF);
    gemm_argmax<<<dim3((HW / BM) * (HW / BN)), 256, 0, stream>>>(aF, bF, packed);
    loss_kernel<<<dim3(HW / 64), 256, 0, stream>>>(a, b, packed, sumsq_a, sumsq_b, out);
}